// Round 2
// baseline (34.757 us; speedup 1.0000x reference)
//
#include <hip/hip_runtime.h>

// Grouped batched matmul: y[t] = x[t] @ W[seg(t)] + b[seg(t)]
// x: [TOTAL, 32] f32, W: [N, 32, 32] f32, b: [N, 32] f32, cnt: [N] i32
//
// One network per block (128 threads = 2 waves), one point per thread.
// W/bias addresses are uniform (blockIdx-derived) -> compiler emits scalar
// (s_load) reads; x row and y row live entirely in VGPRs; no LDS staging,
// no transpose, a single barrier (for the segment-base reduction).

#define BLK 128

__global__ __launch_bounds__(BLK) void mnl_kernel(
    const float* __restrict__ x,
    const float* __restrict__ w,
    const float* __restrict__ bias,
    const int* __restrict__ cnt,
    float* __restrict__ y)
{
    const int n = blockIdx.x;
    const int t = threadIdx.x;

    // ---- exclusive prefix sum: base = sum(cnt[0..n)) ----
    int s = 0;
    for (int j = t; j < n; j += BLK) s += cnt[j];
    #pragma unroll
    for (int off = 32; off > 0; off >>= 1) s += __shfl_xor(s, off, 64);
    __shared__ int sb[BLK / 64];
    if ((t & 63) == 0) sb[t >> 6] = s;
    __syncthreads();
    int base = 0;
    #pragma unroll
    for (int wv = 0; wv < BLK / 64; ++wv) base += sb[wv];

    const int count = cnt[n];
    const float* __restrict__ wn = w + (size_t)n * (32 * 32);  // uniform -> SGPR
    const float* __restrict__ bn = bias + (size_t)n * 32;      // uniform -> SGPR

    for (int p = t; p < count; p += BLK) {
        // ---- load one full x row into registers (8 x dwordx4) ----
        const float4* __restrict__ xr =
            reinterpret_cast<const float4*>(x + (size_t)(base + p) * 32);
        float xv[32];
        #pragma unroll
        for (int k = 0; k < 8; ++k) {
            const float4 v = xr[k];
            xv[4 * k + 0] = v.x;
            xv[4 * k + 1] = v.y;
            xv[4 * k + 2] = v.z;
            xv[4 * k + 3] = v.w;
        }

        // ---- acc = bias (uniform scalar loads) ----
        float acc[32];
        #pragma unroll
        for (int o = 0; o < 32; ++o) acc[o] = bn[o];

        // ---- 1024 fully-unrolled FMAs, W operand from SGPRs ----
        #pragma unroll
        for (int i = 0; i < 32; ++i) {
            const float xi = xv[i];
            #pragma unroll
            for (int o = 0; o < 32; ++o)
                acc[o] = fmaf(xi, wn[i * 32 + o], acc[o]);
        }

        // ---- store full y row (8 x dwordx4) ----
        float4* __restrict__ yr =
            reinterpret_cast<float4*>(y + (size_t)(base + p) * 32);
        #pragma unroll
        for (int k = 0; k < 8; ++k)
            yr[k] = make_float4(acc[4 * k + 0], acc[4 * k + 1],
                                acc[4 * k + 2], acc[4 * k + 3]);
    }
}

extern "C" void kernel_launch(void* const* d_in, const int* in_sizes, int n_in,
                              void* d_out, int out_size, void* d_ws, size_t ws_size,
                              hipStream_t stream) {
    const float* x    = (const float*)d_in[0];
    const float* w    = (const float*)d_in[1];
    const float* bias = (const float*)d_in[2];
    const int*   cnt  = (const int*)d_in[3];
    float*       y    = (float*)d_out;
    const int n_nets  = in_sizes[3];

    mnl_kernel<<<n_nets, BLK, 0, stream>>>(x, w, bias, cnt, y);
}

// Round 3
// 19.048 us; speedup vs baseline: 1.8247x; 1.8247x over previous
//
#include <hip/hip_runtime.h>

// Grouped batched matmul: y[t] = x[t] @ W[seg(t)] + b[seg(t)]
// x: [TOTAL, 32] f32, W: [N, 32, 32] f32, b: [N, 32] f32, cnt: [N] i32
//
// One WAVE per block (64 threads), TWO blocks per network (64 points each).
// - prefix-sum of cnt via pure __shfl_xor (no LDS, no barriers)
// - W float4-loads issued before the scan (independent -> hidden under it)
// - x chunk transposed into LDS, W staged in LDS; 8p x 4o register tile
// - all barriers are single-wave barriers (near-free)

#define NT 64

__global__ __launch_bounds__(NT) void mnl_kernel(
    const float* __restrict__ x,
    const float* __restrict__ w,
    const float* __restrict__ bias,
    const int* __restrict__ cnt,
    float* __restrict__ y)
{
    __shared__ float xT[32][NT];    // 8 KB: transposed x chunk
    __shared__ float Wl[32][32];    // 4 KB: W row-major [in][out]

    const int b = blockIdx.x;
    const int n = b >> 1;           // network id
    const int h = b & 1;            // which half of the segment
    const int t = threadIdx.x;

    // ---- issue W loads immediately (independent of prefix scan) ----
    const float4* __restrict__ wg = reinterpret_cast<const float4*>(w + (size_t)n * 1024);
    const float4 wr0 = wg[t];
    const float4 wr1 = wg[t + 64];
    const float4 wr2 = wg[t + 128];
    const float4 wr3 = wg[t + 192];

    const int o0 = (t & 7) * 4;     // 4 consecutive outputs
    const int p0 = (t >> 3) * 8;    // 8 consecutive points

    const float4 b4 = *reinterpret_cast<const float4*>(bias + (size_t)n * 32 + o0);

    // ---- exclusive prefix sum over cnt via wave reduce (no LDS) ----
    int s = 0;
    for (int j = t; j < n; j += NT) s += cnt[j];
    #pragma unroll
    for (int off = 32; off > 0; off >>= 1) s += __shfl_xor(s, off, 64);
    const int base  = s;
    const int count = cnt[n];

    // ---- stage W into LDS (consecutive b128 writes, conflict-free) ----
    {
        float4* wl4 = reinterpret_cast<float4*>(&Wl[0][0]);
        wl4[t]       = wr0;
        wl4[t + 64]  = wr1;
        wl4[t + 128] = wr2;
        wl4[t + 192] = wr3;
    }
    // visibility of Wl is ordered by the first __syncthreads below

    for (int pc = h * NT; pc < count; pc += 2 * NT) {
        // ---- load one x row per thread (one 128B line per lane) ----
        const int p = pc + t;
        float4 rr[8];
        if (p < count) {
            const float4* __restrict__ xg =
                reinterpret_cast<const float4*>(x + (size_t)(base + p) * 32);
            #pragma unroll
            for (int k = 0; k < 8; ++k) rr[k] = xg[k];
        } else {
            #pragma unroll
            for (int k = 0; k < 8; ++k) rr[k] = make_float4(0.f, 0.f, 0.f, 0.f);
        }

        __syncthreads();  // 1-wave barrier: previous iter's xT reads done / W staged

        // ---- transposed write (banks t%32, 2-way aliased = free) ----
        #pragma unroll
        for (int k = 0; k < 8; ++k) {
            xT[4 * k + 0][t] = rr[k].x;
            xT[4 * k + 1][t] = rr[k].y;
            xT[4 * k + 2][t] = rr[k].z;
            xT[4 * k + 3][t] = rr[k].w;
        }

        __syncthreads();  // 1-wave barrier

        // ---- compute: 8x4 register tile ----
        float acc[8][4] = {};
        #pragma unroll
        for (int i = 0; i < 32; ++i) {
            const float4 xa = *reinterpret_cast<const float4*>(&xT[i][p0]);
            const float4 xb = *reinterpret_cast<const float4*>(&xT[i][p0 + 4]);
            const float4 wv = *reinterpret_cast<const float4*>(&Wl[i][o0]);
            const float xs[8] = {xa.x, xa.y, xa.z, xa.w, xb.x, xb.y, xb.z, xb.w};
            const float ws[4] = {wv.x, wv.y, wv.z, wv.w};
            #pragma unroll
            for (int pp = 0; pp < 8; ++pp)
                #pragma unroll
                for (int oo = 0; oo < 4; ++oo)
                    acc[pp][oo] = fmaf(xs[pp], ws[oo], acc[pp][oo]);
        }

        // ---- epilogue: bias + coalesced float4 stores ----
        #pragma unroll
        for (int pp = 0; pp < 8; ++pp) {
            const int prow = pc + p0 + pp;
            if (prow < count) {
                float4 o;
                o.x = acc[pp][0] + b4.x;
                o.y = acc[pp][1] + b4.y;
                o.z = acc[pp][2] + b4.z;
                o.w = acc[pp][3] + b4.w;
                *reinterpret_cast<float4*>(&y[(size_t)(base + prow) * 32 + o0]) = o;
            }
        }
    }
}

extern "C" void kernel_launch(void* const* d_in, const int* in_sizes, int n_in,
                              void* d_out, int out_size, void* d_ws, size_t ws_size,
                              hipStream_t stream) {
    const float* x    = (const float*)d_in[0];
    const float* w    = (const float*)d_in[1];
    const float* bias = (const float*)d_in[2];
    const int*   cnt  = (const int*)d_in[3];
    float*       y    = (float*)d_out;
    const int n_nets  = in_sizes[3];

    mnl_kernel<<<2 * n_nets, NT, 0, stream>>>(x, w, bias, cnt, y);
}